// Round 1
// baseline (1841.962 us; speedup 1.0000x reference)
//
#include <hip/hip_runtime.h>
#include <stdint.h>

// Problem sizes (fixed by reference)
#define NB   64
#define NIN  512
#define NHID 1024
#define NOUT 512
#define NT   1024

#define LSTRIDE 128   // u16 index-list entries per (b,t), padded w/ sentinel to mult of 8
#define P1 65         // LDS pitch for fc1 weight tile (conflict-free, 513*65*4 = 133380 B)
#define P2 33         // LDS pitch for fc2 weight tile (1025*33*4 = 135300 B)

// Loihi CUBA constants (all exactly representable in fp32)
#define A_I   0.75f      // (4096-1024)/4096
#define A_V   0.96875f   // (4096-128)/4096
#define WSC   64.0f
#define THETA 5120.0f    // 80*64

// ---------------------------------------------------------------------------
// K1a: binarize x (B,Nin,T) fp32 -> bitmask bits1[b][t][iw], iw in 0..15 (u32)
// Coalesced: each block = (b, iw, 256-t chunk); per j the block reads 1KB contig.
// ---------------------------------------------------------------------------
__global__ void __launch_bounds__(256) k_bits1(const float* __restrict__ x,
                                               uint32_t* __restrict__ bits1) {
  int blk = blockIdx.x;          // b*64 + iw*4 + tc
  int b  = blk >> 6;
  int iw = (blk >> 2) & 15;
  int tc = blk & 3;
  int t  = tc * 256 + threadIdx.x;
  const float* xp = x + ((size_t)(b * NIN + iw * 32)) * NT + t;
  uint32_t w = 0;
#pragma unroll
  for (int j = 0; j < 32; ++j) {
    float v = xp[(size_t)j * NT];
    if (v > 0.5f) w |= (1u << j);
  }
  bits1[((size_t)b * NT + t) * 16 + iw] = w;
}

// ---------------------------------------------------------------------------
// Extract per-(b,t) ascending index lists from bitmasks.
// words: u64 words per row (8 for Nin=512, 16 for Nhid=1024).
// sentinel: index of a zeroed LDS weight row (512 / 1024) used for padding,
// so the consumer inner loop is branch-free.
// ---------------------------------------------------------------------------
__global__ void __launch_bounds__(256) k_extract(const uint64_t* __restrict__ bits,
                                                 uint32_t* __restrict__ cnt,
                                                 uint16_t* __restrict__ list,
                                                 int words, int sentinel) {
  int gid = blockIdx.x * 256 + threadIdx.x;   // = b*NT + t
  const uint64_t* wp = bits + (size_t)gid * words;
  uint16_t* lp = list + (size_t)gid * LSTRIDE;
  int c = 0;
  for (int w = 0; w < words; ++w) {
    uint64_t v = wp[w];
    while (v) {
      int j = __builtin_ctzll(v);
      v &= v - 1;
      if (c < LSTRIDE) lp[c] = (uint16_t)((w << 6) + j);
      ++c;
    }
  }
  if (c > LSTRIDE) c = LSTRIDE;     // ~11-sigma safe for this data
  int cp = (c + 7) & ~7;
  for (int k = c; k < cp; ++k) lp[k] = (uint16_t)sentinel;
  cnt[gid] = (uint32_t)c;
}

// ---------------------------------------------------------------------------
// K2: fused fc1 + LIF neuron, emits spike bitmask bits2[b][t][hq] (u64).
// Block = (bq, hq): 4 waves = 4 batches, 64 lanes = 64 hidden neurons.
// Weight slice lds[i][hl] = w1[h0+hl][i] staged once (row 512 = zeros).
// Inner loop: 8-entry chunks, software-pipelined (load chunk k weights while
// accumulating chunk k-1) to hide ds_read latency; next-t list prefetched.
// ---------------------------------------------------------------------------
__global__ void __launch_bounds__(256) k_fc1(const float* __restrict__ w1,
                                             const uint32_t* __restrict__ cnt1,
                                             const uint16_t* __restrict__ list1,
                                             uint64_t* __restrict__ bits2) {
  extern __shared__ float lds[];   // (NIN+1) x P1
  int hq = blockIdx.x & 15;
  int bq = blockIdx.x >> 4;
  int h0 = hq * 64;
  for (int idx = threadIdx.x; idx < NIN * 64; idx += 256) {
    int hl = idx >> 9;             // 0..63
    int i  = idx & (NIN - 1);
    lds[i * P1 + hl] = w1[(size_t)(h0 + hl) * NIN + i];
  }
  if (threadIdx.x < 64) lds[NIN * P1 + threadIdx.x] = 0.0f;  // sentinel row
  __syncthreads();

  int wid  = threadIdx.x >> 6;
  int lane = threadIdx.x & 63;
  int b = bq * 4 + wid;
  size_t bt = (size_t)b * NT;
  float cur = 0.f, vol = 0.f;

  int cnt = cnt1[bt];
  const uint4* Lp = (const uint4*)(list1 + bt * LSTRIDE);
  uint4 c0 = Lp[0], c1 = Lp[1];

  for (int t = 0; t < NT - 1; ++t) {
    // prefetch next timestep's count + first two chunks (hidden under work)
    const uint4* LpN = (const uint4*)(list1 + (bt + t + 1) * LSTRIDE);
    int  cntN = cnt1[bt + t + 1];
    uint4 n0 = LpN[0], n1 = LpN[1];

    float acc = 0.f;
    int nch = (cnt + 7) >> 3;
    if (nch > 0) {
      uint4 cc = c0;
      uint4 cn = c1;
      float wreg[8];
      {
        uint32_t d0 = cc.x, d1 = cc.y, d2 = cc.z, d3 = cc.w;
        wreg[0] = lds[(int)(d0 & 0xffffu) * P1 + lane];
        wreg[1] = lds[(int)(d0 >> 16)    * P1 + lane];
        wreg[2] = lds[(int)(d1 & 0xffffu) * P1 + lane];
        wreg[3] = lds[(int)(d1 >> 16)    * P1 + lane];
        wreg[4] = lds[(int)(d2 & 0xffffu) * P1 + lane];
        wreg[5] = lds[(int)(d2 >> 16)    * P1 + lane];
        wreg[6] = lds[(int)(d3 & 0xffffu) * P1 + lane];
        wreg[7] = lds[(int)(d3 >> 16)    * P1 + lane];
      }
      for (int kc = 1; kc < nch; ++kc) {
        uint4 cl = cn;
        cn = Lp[(kc + 1) < 16 ? (kc + 1) : 15];
        float nv[8];
        uint32_t d0 = cl.x, d1 = cl.y, d2 = cl.z, d3 = cl.w;
        nv[0] = lds[(int)(d0 & 0xffffu) * P1 + lane];
        nv[1] = lds[(int)(d0 >> 16)    * P1 + lane];
        nv[2] = lds[(int)(d1 & 0xffffu) * P1 + lane];
        nv[3] = lds[(int)(d1 >> 16)    * P1 + lane];
        nv[4] = lds[(int)(d2 & 0xffffu) * P1 + lane];
        nv[5] = lds[(int)(d2 >> 16)    * P1 + lane];
        nv[6] = lds[(int)(d3 & 0xffffu) * P1 + lane];
        nv[7] = lds[(int)(d3 >> 16)    * P1 + lane];
        acc += wreg[0]; acc += wreg[1]; acc += wreg[2]; acc += wreg[3];
        acc += wreg[4]; acc += wreg[5]; acc += wreg[6]; acc += wreg[7];
#pragma unroll
        for (int q = 0; q < 8; ++q) wreg[q] = nv[q];
      }
      acc += wreg[0]; acc += wreg[1]; acc += wreg[2]; acc += wreg[3];
      acc += wreg[4]; acc += wreg[5]; acc += wreg[6]; acc += wreg[7];
    }

    cur = A_I * cur + WSC * acc;
    vol = A_V * vol + cur;
    bool s = vol >= THETA;
    vol = s ? 0.f : vol;
    uint64_t m = __ballot(s);
    if (lane == 0) bits2[(bt + t) * 16 + hq] = m;

    cnt = cntN; c0 = n0; c1 = n1; Lp = LpN;
  }
}

// ---------------------------------------------------------------------------
// K3: fused fc2 + LIF + both delay shifts, writes final fp32 spikes.
// Block = (bq, oq): 4 waves = 4 batches; lanes 0..31 & 32..63 split even/odd
// list entries for the same 32 outputs; partials combined via shfl_xor(32).
// Input at time tau is s1[tau-1] (delay 1); output out[p] = spike2[p-1].
// Output buffered 16 timesteps in a bit register -> 64B stores per lane.
// ---------------------------------------------------------------------------
__global__ void __launch_bounds__(256) k_fc2(const float* __restrict__ w2,
                                             const uint32_t* __restrict__ cnt2,
                                             const uint16_t* __restrict__ list2,
                                             float* __restrict__ out) {
  extern __shared__ float lds[];   // (NHID+1) x P2
  int oq = blockIdx.x & 15;
  int bq = blockIdx.x >> 4;
  int o0 = oq * 32;
  for (int idx = threadIdx.x; idx < NHID * 32; idx += 256) {
    int ol = idx >> 10;            // 0..31
    int i  = idx & (NHID - 1);
    lds[i * P2 + ol] = w2[(size_t)(o0 + ol) * NHID + i];
  }
  if (threadIdx.x < 32) lds[NHID * P2 + threadIdx.x] = 0.0f;  // sentinel row
  __syncthreads();

  int wid  = threadIdx.x >> 6;
  int lane = threadIdx.x & 63;
  int half = lane >> 5;
  int ol   = lane & 31;
  int b = bq * 4 + wid;
  int o = o0 + ol;
  size_t bt = (size_t)b * NT;
  float* op = out + ((size_t)b * NOUT + o) * NT;

  float cur = 0.f, vol = 0.f;
  uint32_t sm = 0;                 // 16 output bits; bit for p=0 stays 0
  int cnt = 0;                     // tau=0 input is the zero-shifted padding
  const uint4* Lp = (const uint4*)(list2 + bt * LSTRIDE);
  uint4 c0 = Lp[0], c1 = Lp[1];    // garbage ok, cnt=0

  for (int tau = 0; tau < NT - 1; ++tau) {
    // prefetch list at index tau (consumed at tau+1, i.e. s1[tau])
    const uint4* LpN = (const uint4*)(list2 + (bt + tau) * LSTRIDE);
    int  cntN = cnt2[bt + tau];
    uint4 n0 = LpN[0], n1 = LpN[1];

    float acc = 0.f;
    int nch = (cnt + 7) >> 3;
    uint4 ca = c0, cb = c1;
    for (int kc = 0; kc < nch; ++kc) {
      uint4 cc = ca; ca = cb;
      cb = Lp[(kc + 2) < 16 ? (kc + 2) : 15];
      uint32_t d0 = cc.x, d1 = cc.y, d2 = cc.z, d3 = cc.w;
      int i0 = half ? (int)(d0 >> 16) : (int)(d0 & 0xffffu);
      int i1 = half ? (int)(d1 >> 16) : (int)(d1 & 0xffffu);
      int i2 = half ? (int)(d2 >> 16) : (int)(d2 & 0xffffu);
      int i3 = half ? (int)(d3 >> 16) : (int)(d3 & 0xffffu);
      acc += lds[i0 * P2 + ol];
      acc += lds[i1 * P2 + ol];
      acc += lds[i2 * P2 + ol];
      acc += lds[i3 * P2 + ol];
    }
    acc += __shfl_xor(acc, 32, 64);   // combine even/odd partials

    cur = A_I * cur + WSC * acc;
    vol = A_V * vol + cur;
    bool s = vol >= THETA;
    vol = s ? 0.f : vol;

    int p = tau + 1;                  // output delay shift
    if (s) sm |= (1u << (p & 15));
    if ((p & 15) == 15) {
      if (lane < 32) {
        float vb[16];
#pragma unroll
        for (int q = 0; q < 16; ++q) vb[q] = ((sm >> q) & 1u) ? 1.0f : 0.0f;
        float4* dst = (float4*)(op + (p - 15));
        dst[0] = make_float4(vb[0],  vb[1],  vb[2],  vb[3]);
        dst[1] = make_float4(vb[4],  vb[5],  vb[6],  vb[7]);
        dst[2] = make_float4(vb[8],  vb[9],  vb[10], vb[11]);
        dst[3] = make_float4(vb[12], vb[13], vb[14], vb[15]);
      }
      sm = 0;
    }
    cnt = cntN; c0 = n0; c1 = n1; Lp = LpN;
  }
}

// ---------------------------------------------------------------------------
// ws layout (bytes):
//   bits1  u32[NB*NT*16]      @ 0          (4 MB)
//   cnt1   u32[NB*NT]         @ 4194304    (256 KB)
//   list1  u16[NB*NT*128]     @ 4456448    (16 MB)
//   bits2  u64[NB*NT*16]      @ 21233664   (8 MB)
//   cnt2   u32[NB*NT]         @ 29622272   (256 KB)
//   list2  u16[NB*NT*128]     @ 29884416   (16 MB)   total ~44.5 MB
// ---------------------------------------------------------------------------
extern "C" void kernel_launch(void* const* d_in, const int* in_sizes, int n_in,
                              void* d_out, int out_size, void* d_ws, size_t ws_size,
                              hipStream_t stream) {
  const float* x  = (const float*)d_in[0];
  const float* w1 = (const float*)d_in[1];
  const float* w2 = (const float*)d_in[2];
  float* out = (float*)d_out;

  char* ws = (char*)d_ws;
  uint32_t* bits1 = (uint32_t*)(ws);
  uint32_t* cnt1  = (uint32_t*)(ws + 4194304);
  uint16_t* list1 = (uint16_t*)(ws + 4456448);
  uint64_t* bits2 = (uint64_t*)(ws + 21233664);
  uint32_t* cnt2  = (uint32_t*)(ws + 29622272);
  uint16_t* list2 = (uint16_t*)(ws + 29884416);

  const int LDS1 = (NIN + 1) * P1 * 4;    // 133380
  const int LDS2 = (NHID + 1) * P2 * 4;   // 135300
  (void)hipFuncSetAttribute((const void*)k_fc1,
      hipFuncAttributeMaxDynamicSharedMemorySize, LDS1);
  (void)hipFuncSetAttribute((const void*)k_fc2,
      hipFuncAttributeMaxDynamicSharedMemorySize, LDS2);

  k_bits1 <<<NB * 16 * 4, 256, 0, stream>>>(x, bits1);
  k_extract<<<(NB * NT) / 256, 256, 0, stream>>>((const uint64_t*)bits1, cnt1,
                                                 list1, 8, NIN);
  k_fc1   <<<16 * 16, 256, LDS1, stream>>>(w1, cnt1, list1, bits2);
  k_extract<<<(NB * NT) / 256, 256, 0, stream>>>(bits2, cnt2, list2, 16, NHID);
  k_fc2   <<<16 * 16, 256, LDS2, stream>>>(w2, cnt2, list2, out);
}

// Round 3
// 1409.316 us; speedup vs baseline: 1.3070x; 1.3070x over previous
//
#include <hip/hip_runtime.h>
#include <stdint.h>

// Problem sizes (fixed by reference)
#define NB   64
#define NIN  512
#define NHID 1024
#define NOUT 512
#define NT   1024

#define LSTRIDE 128   // u16 entries per (b,t) list, sentinel-padded to FULL length
#define P1 64         // fc1 tile dword pitch: lanes read same row, cols 0..63 -> 2-way (free)
#define P2 32         // fc2 tile dword pitch: same-row cols 0..31 -> 2-way (free)

// Loihi CUBA constants (exact in fp32)
#define A_I   0.75f
#define A_V   0.96875f
#define WSC   64.0f
#define THETA 5120.0f

// ---------------------------------------------------------------------------
// K1: binarize x (B,Nin,T) fp32 -> bitmask bits1[b][t][iw] (u32), coalesced.
// ---------------------------------------------------------------------------
__global__ void __launch_bounds__(256) k_bits1(const float* __restrict__ x,
                                               uint32_t* __restrict__ bits1) {
  int blk = blockIdx.x;          // b*64 + iw*4 + tc
  int b  = blk >> 6;
  int iw = (blk >> 2) & 15;
  int tc = blk & 3;
  int t  = tc * 256 + threadIdx.x;
  const float* xp = x + ((size_t)(b * NIN + iw * 32)) * NT + t;
  uint32_t w = 0;
#pragma unroll
  for (int j = 0; j < 32; ++j) {
    float v = xp[(size_t)j * NT];
    if (v > 0.5f) w |= (1u << j);
  }
  bits1[((size_t)b * NT + t) * 16 + iw] = w;
}

// ---------------------------------------------------------------------------
// Extract per-(b,t) ascending index lists; pad the FULL LSTRIDE with sentinel
// (consumers read whole 16-entry groups, so tail chunks must be valid
// sentinel entries mapping to a zeroed LDS row; +0.0f adds are bit-neutral).
// ---------------------------------------------------------------------------
__global__ void __launch_bounds__(256) k_extract(const uint64_t* __restrict__ bits,
                                                 uint32_t* __restrict__ cnt,
                                                 uint16_t* __restrict__ list,
                                                 int words, int sentinel) {
  int gid = blockIdx.x * 256 + threadIdx.x;   // = b*NT + t
  const uint64_t* wp = bits + (size_t)gid * words;
  uint16_t* lp = list + (size_t)gid * LSTRIDE;
  int c = 0;
  for (int w = 0; w < words; ++w) {
    uint64_t v = wp[w];
    while (v) {
      int j = __builtin_ctzll(v);
      v &= v - 1;
      if (c < LSTRIDE) lp[c] = (uint16_t)((w << 6) + j);
      ++c;
    }
  }
  if (c > LSTRIDE) c = LSTRIDE;
  cnt[gid] = (uint32_t)c;
  int cp = c;
  if (cp & 1) { lp[cp] = (uint16_t)sentinel; ++cp; }
  uint32_t s2 = (uint32_t)sentinel * 0x10001u;
  uint32_t* lp32 = (uint32_t*)lp;
  for (int k = cp >> 1; k < LSTRIDE / 2; ++k) lp32[k] = s2;
}

// Sequential single-accumulator sums: order = ascending list entries,
// bit-identical to the round-1 (validated, absmax 0.0) kernel.
#define SUM16(ACC, B) do { _Pragma("unroll") \
  for (int q_ = 0; q_ < 16; ++q_) (ACC) += (B)[q_]; } while (0)
#define SUM8(ACC, B) do { _Pragma("unroll") \
  for (int q_ = 0; q_ < 8; ++q_) (ACC) += (B)[q_]; } while (0)

// ---------------------------------------------------------------------------
// K2: fused fc1 + LIF -> spike bitmask bits2[b][t][hq] (u64).
// Block = (bq, hq): 4 waves = 4 batches, 64 lanes = 64 hidden (round-1 map).
// Per t: full next-t list prefetched into 12 uint4 regs (96 entries, ~6.6
// sigma; JIT fallback beyond); inner loop = 16-entry groups with 1-group
// LDS-load lookahead (ping-pong bf0/bf1, fully unrolled, static indexing).
// ---------------------------------------------------------------------------
__global__ void __launch_bounds__(256, 1) k_fc1(const float* __restrict__ w1,
                                                const uint32_t* __restrict__ cnt1,
                                                const uint16_t* __restrict__ list1,
                                                uint64_t* __restrict__ bits2) {
  extern __shared__ float lds[];   // (NIN+1) x 64
  int hq = blockIdx.x & 15, bq = blockIdx.x >> 4;
  int h0 = hq * 64;
  for (int idx = threadIdx.x; idx < NIN * 64; idx += 256) {
    int hl = idx >> 9;             // 0..63
    int i  = idx & (NIN - 1);
    lds[i * P1 + hl] = w1[(size_t)(h0 + hl) * NIN + i];
  }
  if (threadIdx.x < 64) lds[NIN * P1 + threadIdx.x] = 0.0f;  // sentinel row
  __syncthreads();

  int wid = threadIdx.x >> 6, lane = threadIdx.x & 63;
  int b = bq * 4 + wid;
  size_t bt = (size_t)b * NT;
  const uint4* Lbase = (const uint4*)list1;   // chunk kc of (b,t) at [(b*NT+t)*16 + kc]
  float cur = 0.f, vol = 0.f;

  uint4 ct[12], rt[12];
  int cntC = (int)cnt1[bt];
  {
    const uint4* Lp = Lbase + bt * 16;
#pragma unroll
    for (int k = 0; k < 12; ++k) ct[k] = Lp[k];
  }

#define FC1_LOADG(BUF, CA, CB) do {                                             \
    uint4 ca_ = (CA), cb_ = (CB);                                               \
    BUF[0]  = lds[(ca_.x & 0xffffu) * P1 + lane];                               \
    BUF[1]  = lds[(ca_.x >> 16)     * P1 + lane];                               \
    BUF[2]  = lds[(ca_.y & 0xffffu) * P1 + lane];                               \
    BUF[3]  = lds[(ca_.y >> 16)     * P1 + lane];                               \
    BUF[4]  = lds[(ca_.z & 0xffffu) * P1 + lane];                               \
    BUF[5]  = lds[(ca_.z >> 16)     * P1 + lane];                               \
    BUF[6]  = lds[(ca_.w & 0xffffu) * P1 + lane];                               \
    BUF[7]  = lds[(ca_.w >> 16)     * P1 + lane];                               \
    BUF[8]  = lds[(cb_.x & 0xffffu) * P1 + lane];                               \
    BUF[9]  = lds[(cb_.x >> 16)     * P1 + lane];                               \
    BUF[10] = lds[(cb_.y & 0xffffu) * P1 + lane];                               \
    BUF[11] = lds[(cb_.y >> 16)     * P1 + lane];                               \
    BUF[12] = lds[(cb_.z & 0xffffu) * P1 + lane];                               \
    BUF[13] = lds[(cb_.z >> 16)     * P1 + lane];                               \
    BUF[14] = lds[(cb_.w & 0xffffu) * P1 + lane];                               \
    BUF[15] = lds[(cb_.w >> 16)     * P1 + lane];                               \
  } while (0)

#define FC1_BODY(T, CT, RT) do {                                                \
    const int t_ = (T);                                                         \
    const uint4* Ln_ = Lbase + (bt + t_ + 1) * 16;                              \
    _Pragma("unroll")                                                           \
    for (int k = 0; k < 12; ++k) RT[k] = Ln_[k];                                \
    int cntN_ = (int)cnt1[bt + t_ + 1];                                         \
    const uint4* Lc_ = Lbase + (bt + t_) * 16;                                  \
    int ng_ = (cntC + 15) >> 4;   /* wave-uniform: one batch per wave */        \
    float acc = 0.f;                                                            \
    {                                                                           \
      float bf0[16], bf1[16];                                                   \
      FC1_LOADG(bf0, CT[0], CT[1]);                                             \
      _Pragma("unroll")                                                         \
      for (int g = 0; g < 8; ++g) {                                             \
        if (g >= ng_) break;                                                    \
        if (g + 1 < ng_) {                                                      \
          uint4 cA_ = ((2*g+2) < 12) ? CT[(2*g+2) % 12] : Lc_[2*g+2];           \
          uint4 cB_ = ((2*g+3) < 12) ? CT[(2*g+3) % 12] : Lc_[2*g+3];           \
          if ((g & 1) == 0) { FC1_LOADG(bf1, cA_, cB_); }                       \
          else              { FC1_LOADG(bf0, cA_, cB_); }                       \
        }                                                                       \
        if ((g & 1) == 0) { SUM16(acc, bf0); } else { SUM16(acc, bf1); }        \
      }                                                                         \
    }                                                                           \
    cur = A_I * cur + WSC * acc;                                                \
    vol = A_V * vol + cur;                                                      \
    bool s_ = vol >= THETA;                                                     \
    vol = s_ ? 0.f : vol;                                                       \
    unsigned long long m_ = __ballot(s_);                                       \
    if (lane == 0) bits2[(bt + t_) * 16 + hq] = m_;                             \
    cntC = cntN_;                                                               \
  } while (0)

  for (int t = 0; t < NT - 2; t += 2) {
    FC1_BODY(t, ct, rt);
    FC1_BODY(t + 1, rt, ct);
  }
  FC1_BODY(NT - 2, ct, rt);   // t = 1022 (prefetch of t=1023 is in-bounds, unused)
#undef FC1_BODY
#undef FC1_LOADG
}

// ---------------------------------------------------------------------------
// K3: fused fc2 + LIF + both delay shifts -> final fp32 spikes (round-1 map).
// Block = (bq, oq): 4 waves = 4 batches; lanes 0..31 / 32..63 take even/odd
// list entries for the same 32 outputs; halves combined via shfl_xor(32)
// (commutative add -> bit-identical in both halves). Input at tau is
// s1[tau-1]; out[p] = spike2[p-1]; 16-t register-buffered 64 B stores.
// ---------------------------------------------------------------------------
__global__ void __launch_bounds__(256, 1) k_fc2(const float* __restrict__ w2,
                                                const uint32_t* __restrict__ cnt2,
                                                const uint16_t* __restrict__ list2,
                                                float* __restrict__ out) {
  extern __shared__ float lds[];   // (NHID+1) x 32
  int oq = blockIdx.x & 15, bq = blockIdx.x >> 4;
  int o0 = oq * 32;
  for (int idx = threadIdx.x; idx < NHID * 32; idx += 256) {
    int om = idx >> 10;            // 0..31
    int i  = idx & (NHID - 1);
    lds[i * P2 + om] = w2[(size_t)(o0 + om) * NHID + i];
  }
  if (threadIdx.x < 32) lds[NHID * P2 + threadIdx.x] = 0.0f;  // sentinel row
  __syncthreads();

  int wid = threadIdx.x >> 6, lane = threadIdx.x & 63;
  int col = lane & 31;
  int sh  = (lane >> 5) << 4;      // 0 = even entries, 16 = odd entries
  int b = bq * 4 + wid;
  size_t bt = (size_t)b * NT;
  const uint4* Lbase = (const uint4*)list2;
  float* op = out + ((size_t)b * NOUT + o0 + col) * NT;

  float cur = 0.f, vol = 0.f;
  uint32_t sm = 0;
  uint4 ct[8], rt[8];
#pragma unroll
  for (int k = 0; k < 8; ++k)
    ct[k] = make_uint4(0x04000400u, 0x04000400u, 0x04000400u, 0x04000400u);
  int cntC = 0;                    // tau=0 consumes zero-padded s1[-1]

#define FC2_LOADG(BUF, CA, CB) do {                                             \
    uint4 ca_ = (CA), cb_ = (CB);                                               \
    BUF[0] = lds[((ca_.x >> sh) & 0xffffu) * P2 + col];                         \
    BUF[1] = lds[((ca_.y >> sh) & 0xffffu) * P2 + col];                         \
    BUF[2] = lds[((ca_.z >> sh) & 0xffffu) * P2 + col];                         \
    BUF[3] = lds[((ca_.w >> sh) & 0xffffu) * P2 + col];                         \
    BUF[4] = lds[((cb_.x >> sh) & 0xffffu) * P2 + col];                         \
    BUF[5] = lds[((cb_.y >> sh) & 0xffffu) * P2 + col];                         \
    BUF[6] = lds[((cb_.z >> sh) & 0xffffu) * P2 + col];                         \
    BUF[7] = lds[((cb_.w >> sh) & 0xffffu) * P2 + col];                         \
  } while (0)

#define FC2_BODY(TAU, CT, RT) do {                                             \
    const int tau_ = (TAU);                                                     \
    const uint4* Ln_ = Lbase + (bt + tau_) * 16;                                \
    _Pragma("unroll")                                                           \
    for (int k = 0; k < 8; ++k) RT[k] = Ln_[k];                                 \
    int cntN_ = (int)cnt2[bt + tau_];                                           \
    const uint4* Lc_ = Lbase + (bt + tau_) * 16 - 16;   /* list at tau_-1 */    \
    int ng_ = (cntC + 15) >> 4;                                                 \
    float acc = 0.f;                                                            \
    {                                                                           \
      float bf0[8], bf1[8];                                                     \
      FC2_LOADG(bf0, CT[0], CT[1]);                                             \
      _Pragma("unroll")                                                         \
      for (int g = 0; g < 8; ++g) {                                             \
        if (g >= ng_) break;                                                    \
        if (g + 1 < ng_) {                                                      \
          uint4 cA_ = ((2*g+2) < 8) ? CT[(2*g+2) % 8] : Lc_[2*g+2];             \
          uint4 cB_ = ((2*g+3) < 8) ? CT[(2*g+3) % 8] : Lc_[2*g+3];             \
          if ((g & 1) == 0) { FC2_LOADG(bf1, cA_, cB_); }                       \
          else              { FC2_LOADG(bf0, cA_, cB_); }                       \
        }                                                                       \
        if ((g & 1) == 0) { SUM8(acc, bf0); } else { SUM8(acc, bf1); }          \
      }                                                                         \
    }                                                                           \
    acc += __shfl_xor(acc, 32, 64);   /* even+odd halves, commutative */        \
    cur = A_I * cur + WSC * acc;                                                \
    vol = A_V * vol + cur;                                                      \
    bool s_ = vol >= THETA;                                                     \
    vol = s_ ? 0.f : vol;                                                       \
    int p_ = tau_ + 1;                                                          \
    if (s_) sm |= (1u << (p_ & 15));                                            \
    if ((p_ & 15) == 15) {                                                      \
      if (lane < 32) {                                                          \
        float vb[16];                                                           \
        _Pragma("unroll")                                                       \
        for (int q = 0; q < 16; ++q) vb[q] = ((sm >> q) & 1u) ? 1.0f : 0.0f;    \
        float4* dst = (float4*)(op + (p_ - 15));                                \
        dst[0] = make_float4(vb[0],  vb[1],  vb[2],  vb[3]);                    \
        dst[1] = make_float4(vb[4],  vb[5],  vb[6],  vb[7]);                    \
        dst[2] = make_float4(vb[8],  vb[9],  vb[10], vb[11]);                   \
        dst[3] = make_float4(vb[12], vb[13], vb[14], vb[15]);                   \
      }                                                                         \
      sm = 0;                                                                   \
    }                                                                           \
    cntC = cntN_;                                                               \
  } while (0)

  for (int tau = 0; tau < NT - 2; tau += 2) {
    FC2_BODY(tau, ct, rt);
    FC2_BODY(tau + 1, rt, ct);
  }
  FC2_BODY(NT - 2, ct, rt);   // tau = 1022 -> p = 1023, final flush
#undef FC2_BODY
#undef FC2_LOADG
}

// ---------------------------------------------------------------------------
// ws layout (bytes): bits1 u32[64K*16] @0 (4MB); cnt1 @4194304 (256KB);
// list1 u16[64K*128] @4456448 (16MB); bits2 u64[64K*16] @21233664 (8MB);
// cnt2 @29622272 (256KB); list2 @29884416 (16MB).
// ---------------------------------------------------------------------------
extern "C" void kernel_launch(void* const* d_in, const int* in_sizes, int n_in,
                              void* d_out, int out_size, void* d_ws, size_t ws_size,
                              hipStream_t stream) {
  const float* x  = (const float*)d_in[0];
  const float* w1 = (const float*)d_in[1];
  const float* w2 = (const float*)d_in[2];
  float* out = (float*)d_out;

  char* ws = (char*)d_ws;
  uint32_t* bits1 = (uint32_t*)(ws);
  uint32_t* cnt1  = (uint32_t*)(ws + 4194304);
  uint16_t* list1 = (uint16_t*)(ws + 4456448);
  uint64_t* bits2 = (uint64_t*)(ws + 21233664);
  uint32_t* cnt2  = (uint32_t*)(ws + 29622272);
  uint16_t* list2 = (uint16_t*)(ws + 29884416);

  const int LDS1 = (NIN + 1) * P1 * 4;    // 131328
  const int LDS2 = (NHID + 1) * P2 * 4;   // 131200
  (void)hipFuncSetAttribute((const void*)k_fc1,
      hipFuncAttributeMaxDynamicSharedMemorySize, LDS1);
  (void)hipFuncSetAttribute((const void*)k_fc2,
      hipFuncAttributeMaxDynamicSharedMemorySize, LDS2);

  k_bits1 <<<NB * 16 * 4, 256, 0, stream>>>(x, bits1);
  k_extract<<<(NB * NT) / 256, 256, 0, stream>>>((const uint64_t*)bits1, cnt1,
                                                 list1, 8, NIN);
  k_fc1   <<<16 * 16, 256, LDS1, stream>>>(w1, cnt1, list1, bits2);
  k_extract<<<(NB * NT) / 256, 256, 0, stream>>>(bits2, cnt2, list2, 16, NHID);
  k_fc2   <<<16 * 16, 256, LDS2, stream>>>(w2, cnt2, list2, out);
}